// Round 1
// baseline (283.897 us; speedup 1.0000x reference)
//
#include <hip/hip_runtime.h>

// Problem constants (from reference): B=2048, V=256, T=11, K=8, N=8, H=255
constexpr int B_ = 2048;
constexpr int V_ = 256;
constexpr int T_ = 11;
constexpr int K_ = 8;
constexpr int N_ = 8;
constexpr int H_ = 255;

constexpr int TS = 12;   // padded t-stride in hsh (11 -> 12, keeps 16B alignment for b128)
constexpr int KS = 100;  // per-k slab stride (8*12=96 -> 100: banks 4k%32 distinct per k)

// One block per batch element b.
// Phase 1a: coalesced scan of x[b] (88 KB) -> compact nonzero list (one-hot: 88 entries).
// Phase 1b: gather scanner_w, accumulate h[k][n][t] into LDS (relu deferred to phase 2).
// Phase 2:  thread (k=tid&7, base=tid>>3) handles hidden neurons hh=base+32*i,
//           caches h[k][:][:] in registers, accumulates out partials acc[2][T].
// Reduce:   64-lane butterfly + cross-wave LDS combine, 22 outputs written once.
__global__ __launch_bounds__(256, 2)
void scanner_fused(const float* __restrict__ x,    // (B,V,T,K)
                   const float* __restrict__ sw,   // (N,V,K)
                   const float* __restrict__ hw,   // (K*H, N)
                   const float* __restrict__ ow,   // (2, K*H)
                   const float* __restrict__ ob,   // (2,)
                   float* __restrict__ out)        // (B,2,T)
{
    __shared__ float hsh[K_ * KS];   // 800 floats: h accumulator
    __shared__ float wred[4][22];    // per-wave reduction partials
    __shared__ int   cnt;
    __shared__ int   flist[192];
    __shared__ float vlist[192];

    const int tid = threadIdx.x;
    const int b   = blockIdx.x;

    if (tid == 0) cnt = 0;
    for (int i = tid; i < K_ * KS; i += 256) hsh[i] = 0.0f;
    __syncthreads();

    // ---------- phase 1a: scan x for nonzeros (coalesced float4) ----------
    // x-slab per b: V*T*K = 22528 floats = 5632 float4 = 22 iters * 256 threads
    const float4* xb = (const float4*)(x + (size_t)b * (V_ * T_ * K_));
    #pragma unroll
    for (int c = 0; c < 2; ++c) {
        float4 xv[11];  // stage 11 independent loads for MLP
        #pragma unroll
        for (int i = 0; i < 11; ++i)
            xv[i] = xb[tid + (c * 11 + i) * 256];
        #pragma unroll
        for (int i = 0; i < 11; ++i) {
            const int f4 = (tid + (c * 11 + i) * 256) * 4;
            const float vals[4] = {xv[i].x, xv[i].y, xv[i].z, xv[i].w};
            #pragma unroll
            for (int j = 0; j < 4; ++j) {
                if (vals[j] != 0.0f) {
                    int idx = atomicAdd(&cnt, 1);
                    if (idx < 192) { flist[idx] = f4 + j; vlist[idx] = vals[j]; }
                }
            }
        }
    }
    __syncthreads();

    // ---------- phase 1b: gather scanner_w, scatter-accumulate into hsh ----------
    const int m = cnt < 192 ? cnt : 192;
    if (tid < m) {
        const int   f   = flist[tid];
        const float val = vlist[tid];
        const int vv = f / 88;            // V index
        const int tk = f - vv * 88;
        const int t  = tk >> 3;
        const int k  = tk & 7;
        #pragma unroll
        for (int n = 0; n < N_; ++n)
            atomicAdd(&hsh[k * KS + n * TS + t], val * sw[(n * V_ + vv) * K_ + k]);
    }
    __syncthreads();

    // ---------- phase 2: hidden layer + output accumulation ----------
    const int k    = tid & 7;    // slot
    const int base = tid >> 3;   // 0..31

    float hreg[N_][T_];          // relu(h[k][n][t]) cached in registers
    #pragma unroll
    for (int n = 0; n < N_; ++n)
        #pragma unroll
        for (int t = 0; t < T_; ++t)
            hreg[n][t] = fmaxf(hsh[k * KS + n * TS + t], 0.0f);

    float acc0[T_], acc1[T_];
    #pragma unroll
    for (int t = 0; t < T_; ++t) { acc0[t] = 0.0f; acc1[t] = 0.0f; }

    #pragma unroll
    for (int i = 0; i < 8; ++i) {
        const int hh = base + 32 * i;   // covers 0..255 exactly once; skip hh==255
        if (hh < H_) {
            const int row = k * H_ + hh;
            const float4* hwr = (const float4*)(hw + row * 8);
            const float4 w0 = hwr[0];
            const float4 w1 = hwr[1];
            const float o0 = ow[row];
            const float o1 = ow[K_ * H_ + row];
            #pragma unroll
            for (int t = 0; t < T_; ++t) {
                float pre = w0.x * hreg[0][t];
                pre = fmaf(w0.y, hreg[1][t], pre);
                pre = fmaf(w0.z, hreg[2][t], pre);
                pre = fmaf(w0.w, hreg[3][t], pre);
                pre = fmaf(w1.x, hreg[4][t], pre);
                pre = fmaf(w1.y, hreg[5][t], pre);
                pre = fmaf(w1.z, hreg[6][t], pre);
                pre = fmaf(w1.w, hreg[7][t], pre);
                const float h2 = fmaxf(pre, 0.0f);
                acc0[t] = fmaf(h2, o0, acc0[t]);
                acc1[t] = fmaf(h2, o1, acc1[t]);
            }
        }
    }

    // ---------- reduce: 64-lane butterfly, then cross-wave via LDS ----------
    #pragma unroll
    for (int t = 0; t < T_; ++t) {
        #pragma unroll
        for (int off = 32; off >= 1; off >>= 1) {
            acc0[t] += __shfl_xor(acc0[t], off, 64);
            acc1[t] += __shfl_xor(acc1[t], off, 64);
        }
    }
    const int wave = tid >> 6;
    const int lane = tid & 63;
    if (lane == 0) {
        #pragma unroll
        for (int t = 0; t < T_; ++t) {
            wred[wave][t]      = acc0[t];
            wred[wave][11 + t] = acc1[t];
        }
    }
    __syncthreads();

    if (tid < 22) {
        const float s = wred[0][tid] + wred[1][tid] + wred[2][tid] + wred[3][tid];
        const int o = tid / 11;
        out[(size_t)b * 22 + tid] = s + ob[o];
    }
}

extern "C" void kernel_launch(void* const* d_in, const int* in_sizes, int n_in,
                              void* d_out, int out_size, void* d_ws, size_t ws_size,
                              hipStream_t stream) {
    const float* x  = (const float*)d_in[0];  // (B,V,T,K)
    const float* sw = (const float*)d_in[1];  // (N,V,K)
    const float* hw = (const float*)d_in[2];  // (K*H,N)
    const float* ow = (const float*)d_in[3];  // (2,K*H)
    const float* ob = (const float*)d_in[4];  // (2,)
    float* out = (float*)d_out;               // (B,2,T)

    scanner_fused<<<B_, 256, 0, stream>>>(x, sw, hw, ow, ob, out);
}